// Round 5
// baseline (262.150 us; speedup 1.0000x reference)
//
#include <hip/hip_runtime.h>

typedef unsigned short u16;
typedef __bf16 bf16x8 __attribute__((ext_vector_type(8)));
typedef float f32x4 __attribute__((ext_vector_type(4)));
typedef float f32x16 __attribute__((ext_vector_type(16)));

#define LOG2E 1.44269504088896f

__device__ inline u16 f2b(float f) {
    unsigned u = __float_as_uint(f);
    u += 0x7fff + ((u >> 16) & 1);
    return (u16)(u >> 16);
}
__device__ inline float b2f(u16 u) { return __uint_as_float(((unsigned)u) << 16); }
__device__ inline unsigned pk2(float a, float b) {
    return (unsigned)f2b(a) | ((unsigned)f2b(b) << 16);
}
__device__ inline uint4 pack8(float4 a, float4 b) {
    return uint4{pk2(a.x, a.y), pk2(a.z, a.w), pk2(b.x, b.y), pk2(b.z, b.w)};
}
__device__ inline f32x4 mfma16(uint4 a, uint4 b, f32x4 c) {
    return __builtin_amdgcn_mfma_f32_16x16x32_bf16(
        __builtin_bit_cast(bf16x8, a), __builtin_bit_cast(bf16x8, b), c, 0, 0, 0);
}
__device__ inline f32x16 mfma32(uint4 a, uint4 b, f32x16 c) {
    return __builtin_amdgcn_mfma_f32_32x32x16_bf16(
        __builtin_bit_cast(bf16x8, a), __builtin_bit_cast(bf16x8, b), c, 0, 0, 0);
}
// async global->LDS, 16 B per lane; LDS dest = wave-uniform base + lane*16
__device__ inline void ld16(const u16* g, u16* l) {
    __builtin_amdgcn_global_load_lds(
        (const __attribute__((address_space(1))) unsigned int*)g,
        (__attribute__((address_space(3))) unsigned int*)l, 16, 0, 0);
}

// ---------------------------------------------------------------------------
// Weight prep (f32 -> bf16):
//   WkT[e][d] = Wqk[1][d][e],  WvT[e][d] = Wv[d][e],  Wqb[c][d] = Wqk[0][c][d]
// ---------------------------------------------------------------------------
__global__ __launch_bounds__(256) void prep_w(const float* __restrict__ Wqk,
                                              const float* __restrict__ Wv,
                                              u16* __restrict__ WkT,
                                              u16* __restrict__ WvT,
                                              u16* __restrict__ Wqb) {
    int idx = blockIdx.x * 256 + threadIdx.x;   // 0 .. 196607
    int which = idx >> 16;
    int i = (idx >> 8) & 255;
    int j = idx & 255;
    if (which == 0)
        WkT[i * 256 + j] = f2b(Wqk[65536 + j * 256 + i]);
    else if (which == 1)
        WvT[i * 256 + j] = f2b(Wv[j * 256 + i]);
    else
        Wqb[i * 256 + j] = f2b(Wqk[i * 256 + j]);
}

// ===========================================================================
// 32x32x16-MFMA GEMM skeleton: block = 128 X-rows x 256 cols, 4 waves,
// wave = 32 rows x 8 col-tiles, acc = 8 x f32x16 (128 VGPR).
// LDS slab layout (per k32-step, double-buffered):
//   As[p][s][h][r][8e]: off_u16 = p*4096 + s*2048 + h*1024 + r*8   (r<128)
//   Bs[p][s][h][c][8e]: off_u16 = 8192 + p*8192 + s*4096 + h*2048 + c*8
// Frag reads are two contiguous 512B runs per wave (optimal 8-phase).
// A frag: A[m=lane&31][k=s*16+(lane>>5)*8+j]; B frag: B[n=lane&31][k=...].
// C/D: col=lane&31, row=(reg&3)+8*(reg>>2)+4*(lane>>5).
// ===========================================================================

#define G32_LOADG(k0)                                                     \
    {                                                                     \
        ga0 = ((const float4*)(Arow + (k0)))[0];                          \
        ga1 = ((const float4*)(Arow + (k0)))[1];                          \
        ga2 = ((const float4*)(Arow + (k0)))[2];                          \
        ga3 = ((const float4*)(Arow + (k0)))[3];                          \
        gb0 = *(const uint4*)(Brow + (k0));                               \
        gb1 = *(const uint4*)(Brow + (k0) + 8);                           \
        gb2 = *(const uint4*)(Brow + (k0) + 16);                          \
        gb3 = *(const uint4*)(Brow + (k0) + 24);                          \
    }
#define G32_STORE(p)                                                      \
    {                                                                     \
        *(uint4*)(AsW + (p)*4096) = pack8(ga0, ga1);                      \
        *(uint4*)(AsW + (p)*4096 + 1024) = pack8(ga2, ga3);               \
        *(uint4*)(BsW + (p)*8192) = gb0;                                  \
        *(uint4*)(BsW + (p)*8192 + 2048) = gb1;                           \
        *(uint4*)(BsW + (p)*8192 + 4096) = gb2;                           \
        *(uint4*)(BsW + (p)*8192 + 6144) = gb3;                           \
    }

// ---------------------------------------------------------------------------
// Projection GEMM with transposed C-write: CT[b][d][n] = (X @ Bt^T + bias)^T
// ---------------------------------------------------------------------------
__global__ __launch_bounds__(256, 2) void gemm_proj(const float* __restrict__ A,
                                                    const u16* __restrict__ Bt,
                                                    const float* __restrict__ bias,
                                                    u16* __restrict__ CT) {
    __shared__ __align__(16) u16 lds[24576];   // As 2x4096, Bs 2x8192 (u16)
    u16* As = lds;
    u16* Bs = lds + 8192;

    const int t = threadIdx.x;
    const int r0 = blockIdx.x * 128;
    const int w = t >> 6, lane = t & 63, l31 = lane & 31, h = lane >> 5;

    f32x16 acc[8];
#pragma unroll
    for (int c = 0; c < 8; ++c) acc[c] = (f32x16)0.f;

    const int tr = t >> 1, ts = t & 1;
    const float* Arow = A + (long)(r0 + tr) * 256 + ts * 16;
    const u16* Brow = Bt + t * 256;
    u16* AsW = As + ts * 2048 + tr * 8;
    u16* BsW = Bs + t * 8;
    const u16* AsR = As + h * 1024 + (w * 32 + l31) * 8;
    const u16* BsR = Bs + h * 2048 + l31 * 8;

    float4 ga0, ga1, ga2, ga3;
    uint4 gb0, gb1, gb2, gb3;

    G32_LOADG(0);
    G32_STORE(0);
    __syncthreads();
    for (int k0 = 0; k0 < 256; k0 += 32) {
        const int p = (k0 >> 5) & 1;
        if (k0 + 32 < 256) G32_LOADG(k0 + 32);
#pragma unroll
        for (int s = 0; s < 2; ++s) {
            uint4 af = *(const uint4*)(AsR + p * 4096 + s * 2048);
#pragma unroll
            for (int ct = 0; ct < 8; ++ct) {
                uint4 bf = *(const uint4*)(BsR + p * 8192 + s * 4096 + ct * 256);
                acc[ct] = mfma32(af, bf, acc[ct]);
            }
        }
        if (k0 + 32 < 256) G32_STORE(p ^ 1);
        __syncthreads();
    }

    // epilogue: bias + transpose (two 128-d half passes through LDS)
    const int bb = r0 >> 13, n0 = r0 & 8191;
    u16* Ct = lds;                              // [128 d][136 n] u16 = 34 KB
#pragma unroll
    for (int half = 0; half < 2; ++half) {
        __syncthreads();
#pragma unroll
        for (int c4 = 0; c4 < 4; ++c4) {
            const int ct = half * 4 + c4;
            const int dl = c4 * 32 + l31;
            const float bv = bias[half * 128 + dl];
#pragma unroll
            for (int r = 0; r < 16; ++r) {
                int nl = w * 32 + (r & 3) + 8 * (r >> 2) + 4 * h;
                Ct[dl * 136 + nl] = f2b(acc[ct][r] + bv);
            }
        }
        __syncthreads();
        long off = ((long)bb * 256 + half * 128 + (t >> 1)) * 8192 + n0 + (t & 1) * 64;
        const u16* src = Ct + (t >> 1) * 136 + (t & 1) * 64;
#pragma unroll
        for (int j = 0; j < 8; ++j)
            *(uint4*)(CT + off + j * 8) = *(const uint4*)(src + j * 8);
    }
}

// ---------------------------------------------------------------------------
// Output GEMM: out[b][n][e] = sum_c X[b][n][c]*WfoldT[(b,e)][c] + outb[b][e]
// Same skeleton; C stored row-major f32 directly from 32x32 layout.
// ---------------------------------------------------------------------------
__global__ __launch_bounds__(256, 2) void gemm_out(const float* __restrict__ A,
                                                   const u16* __restrict__ WfoldT,
                                                   const float* __restrict__ outb,
                                                   float* __restrict__ C) {
    __shared__ __align__(16) u16 lds[24576];
    u16* As = lds;
    u16* Bs = lds + 8192;

    const int t = threadIdx.x;
    const int r0 = blockIdx.x * 128;
    const int bb = r0 >> 13;
    const int w = t >> 6, lane = t & 63, l31 = lane & 31, h = lane >> 5;

    f32x16 acc[8];
#pragma unroll
    for (int c = 0; c < 8; ++c) acc[c] = (f32x16)0.f;

    const int tr = t >> 1, ts = t & 1;
    const float* Arow = A + (long)(r0 + tr) * 256 + ts * 16;
    const u16* Brow = WfoldT + (long)bb * 65536 + t * 256;
    u16* AsW = As + ts * 2048 + tr * 8;
    u16* BsW = Bs + t * 8;
    const u16* AsR = As + h * 1024 + (w * 32 + l31) * 8;
    const u16* BsR = Bs + h * 2048 + l31 * 8;

    float4 ga0, ga1, ga2, ga3;
    uint4 gb0, gb1, gb2, gb3;

    G32_LOADG(0);
    G32_STORE(0);
    __syncthreads();
    for (int k0 = 0; k0 < 256; k0 += 32) {
        const int p = (k0 >> 5) & 1;
        if (k0 + 32 < 256) G32_LOADG(k0 + 32);
#pragma unroll
        for (int s = 0; s < 2; ++s) {
            uint4 af = *(const uint4*)(AsR + p * 4096 + s * 2048);
#pragma unroll
            for (int ct = 0; ct < 8; ++ct) {
                uint4 bf = *(const uint4*)(BsR + p * 8192 + s * 4096 + ct * 256);
                acc[ct] = mfma32(af, bf, acc[ct]);
            }
        }
        if (k0 + 32 < 256) G32_STORE(p ^ 1);
        __syncthreads();
    }

#pragma unroll
    for (int ct = 0; ct < 8; ++ct) {
        const int col = ct * 32 + l31;
        const float bv = outb[bb * 256 + col];
#pragma unroll
        for (int r = 0; r < 16; ++r) {
            int row = r0 + w * 32 + (r & 3) + 8 * (r >> 2) + 4 * h;
            C[(long)row * 256 + col] = acc[ct][r] + bv;
        }
    }
}

// ---------------------------------------------------------------------------
// Split-K lam GEMM, 128x128 tiles (16x16 MFMA): lamP[s][(b,e)][d].
// Grid (16, 2, 16).  lamP lives in d_out (dead until gemm_out).
// ---------------------------------------------------------------------------
__global__ __launch_bounds__(256, 4) void gemm_splitk(const u16* __restrict__ VT,
                                                      const u16* __restrict__ PT,
                                                      float* __restrict__ lamP,
                                                      int chunk) {
    __shared__ __align__(16) u16 lds[8192];  // As 128x32, Bs 128x32
    u16* As = lds;
    u16* Bs = lds + 4096;

    const int t = threadIdx.x;
    const int r0 = blockIdx.x * 128;   // (b,e) rows
    const int c0 = blockIdx.y * 128;   // d cols
    const int s = blockIdx.z;
    const int bb = blockIdx.x >> 1;
    const long n0 = (long)s * chunk;
    const int w = t >> 6, lane = t & 63, l15 = lane & 15, q = lane >> 4;

    f32x4 acc[2][8];
#pragma unroll
    for (int rt = 0; rt < 2; ++rt)
#pragma unroll
        for (int c = 0; c < 8; ++c) acc[rt][c] = f32x4{0.f, 0.f, 0.f, 0.f};

    for (int k0 = 0; k0 < chunk; k0 += 32) {
#pragma unroll
        for (int j = 0; j < 2; ++j) {
            int ch = j * 256 + t;
            int br = ch >> 2;
            int bk = (ch & 3) * 8;
            ld16(VT + (long)(r0 + br) * 8192 + n0 + k0 + bk, As + j * 2048 + w * 512);
            ld16(PT + ((long)bb * 256 + c0 + br) * 8192 + n0 + k0 + bk,
                 Bs + j * 2048 + w * 512);
        }
        __syncthreads();
        uint4 af0 = *(const uint4*)(As + (w * 32 + l15) * 32 + q * 8);
        uint4 af1 = *(const uint4*)(As + (w * 32 + 16 + l15) * 32 + q * 8);
#pragma unroll
        for (int c = 0; c < 8; ++c) {
            uint4 bf = *(const uint4*)(Bs + (c * 16 + l15) * 32 + q * 8);
            acc[0][c] = mfma16(af0, bf, acc[0][c]);
            acc[1][c] = mfma16(af1, bf, acc[1][c]);
        }
        __syncthreads();
    }

    float* outp = lamP + (long)s * 524288;
#pragma unroll
    for (int rt = 0; rt < 2; ++rt)
#pragma unroll
        for (int c = 0; c < 8; ++c) {
            int col = c0 + c * 16 + l15;
#pragma unroll
            for (int r = 0; r < 4; ++r) {
                int row = r0 + w * 32 + rt * 16 + q * 4 + r;
                outp[(long)row * 256 + col] = acc[rt][c][r];
            }
        }
}

// ---------------------------------------------------------------------------
// lamT[i] = sum_s lamP[s][i]
// ---------------------------------------------------------------------------
__global__ __launch_bounds__(256) void reduce_lam(const float* __restrict__ lamP,
                                                  float* __restrict__ lamT, int S) {
    int i = blockIdx.x * 256 + threadIdx.x;  // float4 index, 131072 total
    float4 v = ((const float4*)lamP)[i];
    for (int s = 1; s < S; ++s) {
        float4 p = ((const float4*)(lamP + (long)s * 524288))[i];
        v.x += p.x; v.y += p.y; v.z += p.z; v.w += p.w;
    }
    ((float4*)lamT)[i] = v;
}

// ---------------------------------------------------------------------------
// Fold GEMM: WfoldT[(b,e)][c] = sum_d bnT[(b,e)][d] * Wqb[c][d].
// ---------------------------------------------------------------------------
__global__ __launch_bounds__(256, 4) void gemm_fold(const u16* __restrict__ Abn,
                                                    const u16* __restrict__ Wqb,
                                                    u16* __restrict__ WfoldT) {
    __shared__ __align__(16) u16 lds[4096];  // As 64x32, Bs 64x32
    u16* As = lds;
    u16* Bs = lds + 2048;

    const int t = threadIdx.x;
    const int r0 = blockIdx.x * 64;
    const int c0 = blockIdx.y * 64;
    const int w = t >> 6, lane = t & 63, l15 = lane & 15, q = lane >> 4;

    f32x4 acc[4];
#pragma unroll
    for (int c = 0; c < 4; ++c) acc[c] = f32x4{0.f, 0.f, 0.f, 0.f};

    const int br = t >> 2;
    const int bk = (t & 3) * 8;

    for (int k0 = 0; k0 < 256; k0 += 32) {
        ld16(Abn + (long)(r0 + br) * 256 + k0 + bk, As + w * 512);
        ld16(Wqb + (long)(c0 + br) * 256 + k0 + bk, Bs + w * 512);
        __syncthreads();
        uint4 af = *(const uint4*)(As + (w * 16 + l15) * 32 + q * 8);
#pragma unroll
        for (int c = 0; c < 4; ++c) {
            uint4 bf = *(const uint4*)(Bs + (c * 16 + l15) * 32 + q * 8);
            acc[c] = mfma16(af, bf, acc[c]);
        }
        __syncthreads();
    }

#pragma unroll
    for (int c = 0; c < 4; ++c) {
        int col = c0 + c * 16 + l15;
#pragma unroll
        for (int r = 0; r < 4; ++r) {
            int row = r0 + w * 16 + q * 4 + r;
            WfoldT[(long)row * 256 + col] = f2b(acc[c][r]);
        }
    }
}

// ---------------------------------------------------------------------------
// In-place softmax over each contiguous 8192-row of KT ([b*256+d][8192]).
// ---------------------------------------------------------------------------
__global__ __launch_bounds__(64) void softmax_rows(u16* __restrict__ KT) {
    const int row = blockIdx.x;
    const int lane = threadIdx.x;
    u16* p = KT + (long)row * 8192;

    uint4 buf[16];
#pragma unroll
    for (int i = 0; i < 16; ++i) buf[i] = *(const uint4*)(p + (i * 64 + lane) * 8);

    float m = -1e30f;
#pragma unroll
    for (int i = 0; i < 16; ++i) {
        const unsigned* u = (const unsigned*)&buf[i];
#pragma unroll
        for (int j = 0; j < 4; ++j) {
            m = fmaxf(m, fmaxf(b2f((u16)(u[j] & 0xffff)), b2f((u16)(u[j] >> 16))));
        }
    }
#pragma unroll
    for (int s = 32; s > 0; s >>= 1) m = fmaxf(m, __shfl_xor(m, s, 64));

    float sum = 0.f;
#pragma unroll
    for (int i = 0; i < 16; ++i) {
        const unsigned* u = (const unsigned*)&buf[i];
#pragma unroll
        for (int j = 0; j < 4; ++j) {
            sum += exp2f((b2f((u16)(u[j] & 0xffff)) - m) * LOG2E);
            sum += exp2f((b2f((u16)(u[j] >> 16)) - m) * LOG2E);
        }
    }
#pragma unroll
    for (int s = 32; s > 0; s >>= 1) sum += __shfl_xor(sum, s, 64);
    float rl = 1.0f / sum;

#pragma unroll
    for (int i = 0; i < 16; ++i) {
        unsigned* u = (unsigned*)&buf[i];
#pragma unroll
        for (int j = 0; j < 4; ++j) {
            float a = exp2f((b2f((u16)(u[j] & 0xffff)) - m) * LOG2E) * rl;
            float b = exp2f((b2f((u16)(u[j] >> 16)) - m) * LOG2E) * rl;
            u[j] = (unsigned)f2b(a) | ((unsigned)f2b(b) << 16);
        }
        *(uint4*)(p + (i * 64 + lane) * 8) = buf[i];
    }
}

// ---------------------------------------------------------------------------
// BatchNorm over lam^T[(b*256+e)][d]: stats per d over 2048 (b,e) values.
// ---------------------------------------------------------------------------
__global__ __launch_bounds__(256) void bn_kernel(const float* __restrict__ lamT,
                                                 const float* __restrict__ gamma,
                                                 const float* __restrict__ beta,
                                                 u16* __restrict__ bnT) {
    const int d = blockIdx.x;
    const int t = threadIdx.x;
    float vals[8];
    float s = 0.f, ss = 0.f;
#pragma unroll
    for (int i = 0; i < 8; ++i) {
        float v = lamT[(long)(i * 256 + t) * 256 + d];
        vals[i] = v;
        s += v;
        ss += v * v;
    }
#pragma unroll
    for (int sh = 32; sh > 0; sh >>= 1) {
        s += __shfl_xor(s, sh, 64);
        ss += __shfl_xor(ss, sh, 64);
    }
    __shared__ float red[8];
    int w = t >> 6;
    if ((t & 63) == 0) {
        red[w] = s;
        red[w + 4] = ss;
    }
    __syncthreads();
    s = red[0] + red[1] + red[2] + red[3];
    ss = red[4] + red[5] + red[6] + red[7];
    float mean = s * (1.f / 2048.f);
    float var = ss * (1.f / 2048.f) - mean * mean;
    float scale = gamma[d] * rsqrtf(var + 1e-5f);
    float shift = beta[d] - mean * scale;
#pragma unroll
    for (int i = 0; i < 8; ++i)
        bnT[(long)(i * 256 + t) * 256 + d] = f2b(vals[i] * scale + shift);
}

// ---------------------------------------------------------------------------
// outb[b][e] = sum_d bq[d] * bnT[b][e][d]   (folded query bias)
// ---------------------------------------------------------------------------
__global__ __launch_bounds__(256) void outb_kernel(const float* __restrict__ bq,
                                                   const u16* __restrict__ bnT,
                                                   float* __restrict__ outb) {
    int b = blockIdx.x, e = threadIdx.x;
    const u16* rowp = bnT + ((long)b * 256 + e) * 256;
    float s = 0.f;
    for (int dd = 0; dd < 256; ++dd) s += bq[dd] * b2f(rowp[dd]);
    outb[b * 256 + e] = s;
}

// ---------------------------------------------------------------------------
extern "C" void kernel_launch(void* const* d_in, const int* in_sizes, int n_in,
                              void* d_out, int out_size, void* d_ws, size_t ws_size,
                              hipStream_t stream) {
    const float* feat = (const float*)d_in[0];   // (8,8192,256) f32
    const float* W_qk = (const float*)d_in[1];   // (2,256,256) f32
    const float* b_qk = (const float*)d_in[2];   // (2,256) f32
    const float* W_v = (const float*)d_in[3];    // (256,256) f32
    const float* b_v = (const float*)d_in[4];    // (256,) f32
    const float* gamma = (const float*)d_in[5];  // (256,) f32
    const float* beta = (const float*)d_in[6];   // (256,) f32
    float* out = (float*)d_out;                  // (8,8192,256) f32

    char* ws = (char*)d_ws;
    u16* KT = (u16*)(ws);                        // [b][d][n] 32 MiB (P after softmax)
    u16* VT = (u16*)(ws + 33554432);             // [b][e][n] 32 MiB
    u16* WkT = (u16*)(ws + 67108864);            // 128 KiB
    u16* WvT = (u16*)(ws + 67239936);            // 128 KiB
    u16* Wqb = (u16*)(ws + 67371008);            // 128 KiB
    float* lamT = (float*)(ws + 67502080);       // 2 MiB (ends ~66.4 MiB, proven safe)
    // lamP partials live in d_out (67 MB f32, dead until gemm_out)
    float* lamPd = (float*)d_out;
    // post-splitk buffers alias the dead P region (KT):
    u16* bnT = (u16*)ws;                         // 1 MiB
    u16* WfoldT = (u16*)(ws + 2097152);          // 1 MiB
    float* outb = (float*)(ws + 4194304);        // 8 KiB

    // 1. weight prep
    prep_w<<<768, 256, 0, stream>>>(W_qk, W_v, WkT, WvT, Wqb);
    // 2. K^T and V^T projections (32x32 MFMA, double-buffered)
    gemm_proj<<<512, 256, 0, stream>>>(feat, WkT, b_qk + 256, KT);
    gemm_proj<<<512, 256, 0, stream>>>(feat, WvT, b_v, VT);
    // 3. in-place softmax over n -> P^T
    softmax_rows<<<2048, 64, 0, stream>>>(KT);
    // 4. split-K lam partials (into d_out) + reduce
    gemm_splitk<<<dim3(16, 2, 16), 256, 0, stream>>>(VT, KT, lamPd, 512);
    reduce_lam<<<512, 256, 0, stream>>>(lamPd, lamT, 16);
    // 5. BN -> bn^T bf16 (aliases dead P region)
    bn_kernel<<<256, 256, 0, stream>>>(lamT, gamma, beta, bnT);
    // 6. folded query bias
    outb_kernel<<<8, 256, 0, stream>>>(b_qk, bnT, outb);
    // 7. Wfold^T = bn^T @ Wq^T
    gemm_fold<<<dim3(32, 4), 256, 0, stream>>>(bnT, Wqb, WfoldT);
    // 8. out = X @ Wfold (+outb)
    gemm_out<<<512, 256, 0, stream>>>(feat, WfoldT, outb, out);
}